// Round 5
// baseline (397.312 us; speedup 1.0000x reference)
//
#include <hip/hip_runtime.h>

#define EPS 1e-8f
#define LAM 0.01f

constexpr int BS = 256;
constexpr int L  = 2048;
constexpr int N  = 128;
constexpr int CHUNK  = 128;          // rows per block; 8 groups x 16 consecutive rows
constexpr int NCHUNK = L / CHUNK;    // 16

typedef float v4f __attribute__((ext_vector_type(4)));

// ws layout (float indices):
//   [WS_S1 , WS_S1 + BS*NCHUNK)  S1 partial per (batch, chunk)
//   [WS_S2 , WS_S2 + BS*NCHUNK)  S2 partial per (batch, chunk)
//   [WS_RES, WS_RES + 4*BS)      res[k][b]: k=0 sharpe_list, 1 sharpe, 2 E, 3 var
//   [WS_CNT, ...)                int region: cnt[BS] per-batch done counters, cnt[BS]=global
// Counters are zeroed by a captured hipMemsetAsync every call; partials/res slots
// are fully rewritten for live chunks each call (dead slots never read).
constexpr int WS_S1  = 0;
constexpr int WS_S2  = BS * NCHUNK;
constexpr int WS_RES = 2 * BS * NCHUNK;
constexpr int WS_CNT = WS_RES + 4 * BS;

__device__ __forceinline__ v4f ldnt(const float* p) {
    return __builtin_nontemporal_load(reinterpret_cast<const v4f*>(p));
}

__device__ __forceinline__ float rowdot(const v4f wv, const v4f pi, const v4f pj) {
    float acc = 0.0f;
    #pragma unroll
    for (int i = 0; i < 4; ++i) {
        float r = (pj[i] - pi[i]) * __builtin_amdgcn_rcpf(pi[i]);
        r = (r <= 2.0f) ? r : 0.0f;
        acc += wv[i] * r;
    }
    return acc;
}

__global__ __launch_bounds__(256) void rp_kernel(
    const float* __restrict__ w,      // [BS][L][N]
    const float* __restrict__ price,  // [BS][L+1][N]
    const int*  __restrict__ pred_sz, // [BS]
    float* __restrict__ ws,
    float* __restrict__ out)
{
    const int b     = blockIdx.x / NCHUNK;
    const int chunk = blockIdx.x % NCHUNK;
    const int n     = pred_sz[b];

    const int start = chunk * CHUNK;
    if (start >= n) return;                 // dead block: no loads, no counters
    const int end = min(start + CHUNK, n);
    const int nc  = (n + CHUNK - 1) / CHUNK;   // live chunks for this batch

    const int tid  = threadIdx.x;
    const int grp  = tid >> 5;
    const int lane = tid & 31;

    const int rs = start + grp * 16;        // this group's 16 consecutive rows
    const int re = min(rs + 16, end);

    float s1 = 0.0f, s2 = 0.0f;

    if (re - rs == 16) {
        // ---- fast path: 16 full rows, price row carried in registers ----
        const float* wp = w     + ((size_t)b * L       + rs) * N + lane * 4;
        const float* pp = price + ((size_t)b * (L + 1) + rs) * N + lane * 4;

        v4f pv = ldnt(pp);                   // price row rs
        #pragma unroll
        for (int half = 0; half < 2; ++half) {
            float A[8];
            #pragma unroll
            for (int r = 0; r < 8; ++r) {
                const int rr = half * 8 + r;
                const v4f pj = ldnt(pp + (size_t)(rr + 1) * N);
                const v4f wv = ldnt(wp + (size_t)rr * N);
                A[r] = rowdot(wv, pv, pj);
                pv = pj;                     // row rr's P_j is row rr+1's P_i
            }
            // Butterfly transpose-reduce over 8 rows x 32 lanes.
            #pragma unroll
            for (int k = 0; k < 3; ++k) {
                const int  m  = 1 << k;
                const bool hi = (lane & m) != 0;
                #pragma unroll
                for (int t = 0; t < (4 >> k); ++t) {
                    const float send = hi ? A[2 * t] : A[2 * t + 1];
                    const float recv = __shfl_xor(send, m);
                    A[t] = (hi ? A[2 * t + 1] : A[2 * t]) + recv;
                }
            }
            float v = A[0] + __shfl_xor(A[0], 8);
            v += __shfl_xor(v, 16);
            const float vm = ((lane & 24) == 0) ? v : 0.0f;  // keep 1 of 4 copies
            s1 += vm;
            s2 += vm * vm;
        }
    } else if (rs < end) {
        // ---- tail path: < 16 rows (at most one group per batch) ----
        const float* wp = w     + ((size_t)b * L       + rs) * N + lane * 4;
        const float* pp = price + ((size_t)b * (L + 1) + rs) * N + lane * 4;
        for (int l = rs; l < re; ++l, wp += N, pp += N) {
            const v4f pi = ldnt(pp);
            const v4f pj = ldnt(pp + N);
            const v4f wv = ldnt(wp);
            float acc = rowdot(wv, pi, pj);
            #pragma unroll
            for (int m = 1; m < 32; m <<= 1)
                acc += __shfl_xor(acc, m);
            if (lane == 0) { s1 += acc; s2 += acc * acc; }
        }
    }

    // Reduce s1/s2 across group, then across the 8 groups.
    #pragma unroll
    for (int m = 1; m < 32; m <<= 1) {
        s1 += __shfl_xor(s1, m);
        s2 += __shfl_xor(s2, m);
    }
    __shared__ float ls1[8], ls2[8];
    __shared__ int s_bl, s_gl;
    if (lane == 0) { ls1[grp] = s1; ls2[grp] = s2; }
    __syncthreads();

    int* cnt = (int*)(ws + WS_CNT);

    if (tid == 0) {
        float t1 = 0.0f, t2 = 0.0f;
        #pragma unroll
        for (int i = 0; i < 8; ++i) { t1 += ls1[i]; t2 += ls2[i]; }
        ws[WS_S1 + b * NCHUNK + chunk] = t1;
        ws[WS_S2 + b * NCHUNK + chunk] = t2;
        __threadfence();                              // release partials
        const int old = atomicAdd(&cnt[b], 1);
        s_bl = (old == nc - 1);
    }
    __syncthreads();
    if (!s_bl) return;                                // uniform per block

    // ---- batch-last: reduce this batch's partials, write per-batch stats ----
    if (tid == 0) {
        __threadfence();                              // acquire partials
        float t1 = 0.0f, t2 = 0.0f;
        for (int c = 0; c < nc; ++c) {
            t1 += ws[WS_S1 + b * NCHUNK + c];
            t2 += ws[WS_S2 + b * NCHUNK + c];
        }
        const float fn    = (float)n;
        const float E     = t1 / fn;
        const float var   = (t2 - fn * E * E) / (fn - 1.0f);
        const float denom = sqrtf(var + EPS);
        ws[WS_RES + 0 * BS + b] = E - LAM / denom;    // sharpe_list
        ws[WS_RES + 1 * BS + b] = E / denom;          // sharpe
        ws[WS_RES + 2 * BS + b] = E;
        ws[WS_RES + 3 * BS + b] = var;
        __threadfence();                              // release res
        const int g = atomicAdd(&cnt[BS], 1);
        s_gl = (g == BS - 1);
    }
    __syncthreads();
    if (!s_gl) return;

    // ---- global-last: 256->4 mean reduction, write outputs ----
    __threadfence();                                  // acquire res
    float v0 = ws[WS_RES + 0 * BS + tid];
    float v1 = ws[WS_RES + 1 * BS + tid];
    float v2 = ws[WS_RES + 2 * BS + tid];
    float v3 = ws[WS_RES + 3 * BS + tid];

    __shared__ float red[4][BS];
    red[0][tid] = v0; red[1][tid] = v1; red[2][tid] = v2; red[3][tid] = v3;
    __syncthreads();
    #pragma unroll
    for (int s = BS / 2; s > 0; s >>= 1) {
        if (tid < s) {
            red[0][tid] += red[0][tid + s];
            red[1][tid] += red[1][tid + s];
            red[2][tid] += red[2][tid + s];
            red[3][tid] += red[3][tid + s];
        }
        __syncthreads();
    }
    if (tid == 0) {
        out[0] = -red[0][0] / (float)BS;
        out[1] = -red[1][0] / (float)BS;
        out[2] =  red[2][0] / (float)BS;
        out[3] =  red[3][0] / (float)BS;
    }
}

extern "C" void kernel_launch(void* const* d_in, const int* in_sizes, int n_in,
                              void* d_out, int out_size, void* d_ws, size_t ws_size,
                              hipStream_t stream) {
    const float* w     = (const float*)d_in[0];  // pred_weights [256][2048][128]
    const float* price = (const float*)d_in[1];  // price_list   [256][2049][128]
    const int*   psz   = (const int*)d_in[2];    // pred_sz      [256]
    float* out = (float*)d_out;
    float* ws  = (float*)d_ws;

    // Zero the (BS+1) int counters (captured as a memset node).
    hipMemsetAsync((char*)d_ws + WS_CNT * sizeof(float), 0,
                   (BS + 1) * sizeof(int), stream);
    rp_kernel<<<BS * NCHUNK, 256, 0, stream>>>(w, price, psz, ws, out);
}

// Round 6
// 365.288 us; speedup vs baseline: 1.0877x; 1.0877x over previous
//
#include <hip/hip_runtime.h>

#define EPS 1e-8f
#define LAM 0.01f

constexpr int BS = 256;
constexpr int L  = 2048;
constexpr int N  = 128;
constexpr int CHUNK  = 128;          // rows per block; 8 groups x 16 consecutive rows
constexpr int NCHUNK = L / CHUNK;    // 16

typedef float v4f __attribute__((ext_vector_type(4)));

// ws layout (float indices):
//   [WS_S1 , WS_S1 + BS*NCHUNK)  S1 partial per (batch, chunk)
//   [WS_S2 , WS_S2 + BS*NCHUNK)  S2 partial per (batch, chunk)
//   [WS_RES, WS_RES + 4*BS)      res[k][b]: k=0 sharpe_list, 1 sharpe, 2 E, 3 var
//   [WS_CNT, ...)                int region: cnt[BS] per-batch done counters, cnt[BS]=global
// Counters are zeroed by a captured hipMemsetAsync every call; partials/res slots
// are fully rewritten for live chunks each call (dead slots never read).
constexpr int WS_S1  = 0;
constexpr int WS_S2  = BS * NCHUNK;
constexpr int WS_RES = 2 * BS * NCHUNK;
constexpr int WS_CNT = WS_RES + 4 * BS;

__device__ __forceinline__ v4f ld4(const float* p) {
    return *reinterpret_cast<const v4f*>(p);
}

__device__ __forceinline__ float rowdot(const v4f wv, const v4f pi, const v4f pj) {
    float acc = 0.0f;
    #pragma unroll
    for (int i = 0; i < 4; ++i) {
        float r = (pj[i] - pi[i]) * __builtin_amdgcn_rcpf(pi[i]);
        r = (r <= 2.0f) ? r : 0.0f;
        acc += wv[i] * r;
    }
    return acc;
}

__global__ __launch_bounds__(256) void rp_kernel(
    const float* __restrict__ w,      // [BS][L][N]
    const float* __restrict__ price,  // [BS][L+1][N]
    const int*  __restrict__ pred_sz, // [BS]
    float* __restrict__ ws,
    float* __restrict__ out)
{
    const int b     = blockIdx.x / NCHUNK;
    const int chunk = blockIdx.x % NCHUNK;
    const int n     = pred_sz[b];

    const int start = chunk * CHUNK;
    if (start >= n) return;                 // dead block: no loads, no counters
    const int end = min(start + CHUNK, n);
    const int nc  = (n + CHUNK - 1) / CHUNK;   // live chunks for this batch

    const int tid  = threadIdx.x;
    const int grp  = tid >> 5;
    const int lane = tid & 31;

    const int rs = start + grp * 16;        // this group's 16 consecutive rows
    const int re = min(rs + 16, end);

    float s1 = 0.0f, s2 = 0.0f;

    if (re - rs == 16) {
        // ---- fast path: 16 full rows, price row carried in registers ----
        const float* wp = w     + ((size_t)b * L       + rs) * N + lane * 4;
        const float* pp = price + ((size_t)b * (L + 1) + rs) * N + lane * 4;

        v4f pv = ld4(pp);                    // price row rs
        #pragma unroll
        for (int half = 0; half < 2; ++half) {
            float A[8];
            #pragma unroll
            for (int r = 0; r < 8; ++r) {
                const int rr = half * 8 + r;
                const v4f pj = ld4(pp + (size_t)(rr + 1) * N);
                const v4f wv = ld4(wp + (size_t)rr * N);
                A[r] = rowdot(wv, pv, pj);
                pv = pj;                     // row rr's P_j is row rr+1's P_i
            }
            // Butterfly transpose-reduce over 8 rows x 32 lanes.
            #pragma unroll
            for (int k = 0; k < 3; ++k) {
                const int  m  = 1 << k;
                const bool hi = (lane & m) != 0;
                #pragma unroll
                for (int t = 0; t < (4 >> k); ++t) {
                    const float send = hi ? A[2 * t] : A[2 * t + 1];
                    const float recv = __shfl_xor(send, m);
                    A[t] = (hi ? A[2 * t + 1] : A[2 * t]) + recv;
                }
            }
            float v = A[0] + __shfl_xor(A[0], 8);
            v += __shfl_xor(v, 16);
            const float vm = ((lane & 24) == 0) ? v : 0.0f;  // keep 1 of 4 copies
            s1 += vm;
            s2 += vm * vm;
        }
    } else if (rs < end) {
        // ---- tail path: < 16 rows (at most one group per batch) ----
        const float* wp = w     + ((size_t)b * L       + rs) * N + lane * 4;
        const float* pp = price + ((size_t)b * (L + 1) + rs) * N + lane * 4;
        for (int l = rs; l < re; ++l, wp += N, pp += N) {
            const v4f pi = ld4(pp);
            const v4f pj = ld4(pp + N);
            const v4f wv = ld4(wp);
            float acc = rowdot(wv, pi, pj);
            #pragma unroll
            for (int m = 1; m < 32; m <<= 1)
                acc += __shfl_xor(acc, m);
            if (lane == 0) { s1 += acc; s2 += acc * acc; }
        }
    }

    // Reduce s1/s2 across group, then across the 8 groups.
    #pragma unroll
    for (int m = 1; m < 32; m <<= 1) {
        s1 += __shfl_xor(s1, m);
        s2 += __shfl_xor(s2, m);
    }
    __shared__ float ls1[8], ls2[8];
    __shared__ int s_bl, s_gl;
    if (lane == 0) { ls1[grp] = s1; ls2[grp] = s2; }
    __syncthreads();

    int* cnt = (int*)(ws + WS_CNT);

    if (tid == 0) {
        float t1 = 0.0f, t2 = 0.0f;
        #pragma unroll
        for (int i = 0; i < 8; ++i) { t1 += ls1[i]; t2 += ls2[i]; }
        ws[WS_S1 + b * NCHUNK + chunk] = t1;
        ws[WS_S2 + b * NCHUNK + chunk] = t2;
        __threadfence();                              // release partials
        const int old = atomicAdd(&cnt[b], 1);
        s_bl = (old == nc - 1);
    }
    __syncthreads();
    if (!s_bl) return;                                // uniform per block

    // ---- batch-last: reduce this batch's partials, write per-batch stats ----
    if (tid == 0) {
        __threadfence();                              // acquire partials
        float t1 = 0.0f, t2 = 0.0f;
        for (int c = 0; c < nc; ++c) {
            t1 += ws[WS_S1 + b * NCHUNK + c];
            t2 += ws[WS_S2 + b * NCHUNK + c];
        }
        const float fn    = (float)n;
        const float E     = t1 / fn;
        const float var   = (t2 - fn * E * E) / (fn - 1.0f);
        const float denom = sqrtf(var + EPS);
        ws[WS_RES + 0 * BS + b] = E - LAM / denom;    // sharpe_list
        ws[WS_RES + 1 * BS + b] = E / denom;          // sharpe
        ws[WS_RES + 2 * BS + b] = E;
        ws[WS_RES + 3 * BS + b] = var;
        __threadfence();                              // release res
        const int g = atomicAdd(&cnt[BS], 1);
        s_gl = (g == BS - 1);
    }
    __syncthreads();
    if (!s_gl) return;

    // ---- global-last: 256->4 mean reduction, write outputs ----
    __threadfence();                                  // acquire res
    float v0 = ws[WS_RES + 0 * BS + tid];
    float v1 = ws[WS_RES + 1 * BS + tid];
    float v2 = ws[WS_RES + 2 * BS + tid];
    float v3 = ws[WS_RES + 3 * BS + tid];

    __shared__ float red[4][BS];
    red[0][tid] = v0; red[1][tid] = v1; red[2][tid] = v2; red[3][tid] = v3;
    __syncthreads();
    #pragma unroll
    for (int s = BS / 2; s > 0; s >>= 1) {
        if (tid < s) {
            red[0][tid] += red[0][tid + s];
            red[1][tid] += red[1][tid + s];
            red[2][tid] += red[2][tid + s];
            red[3][tid] += red[3][tid + s];
        }
        __syncthreads();
    }
    if (tid == 0) {
        out[0] = -red[0][0] / (float)BS;
        out[1] = -red[1][0] / (float)BS;
        out[2] =  red[2][0] / (float)BS;
        out[3] =  red[3][0] / (float)BS;
    }
}

extern "C" void kernel_launch(void* const* d_in, const int* in_sizes, int n_in,
                              void* d_out, int out_size, void* d_ws, size_t ws_size,
                              hipStream_t stream) {
    const float* w     = (const float*)d_in[0];  // pred_weights [256][2048][128]
    const float* price = (const float*)d_in[1];  // price_list   [256][2049][128]
    const int*   psz   = (const int*)d_in[2];    // pred_sz      [256]
    float* out = (float*)d_out;
    float* ws  = (float*)d_ws;

    // Zero the (BS+1) int counters (captured as a memset node).
    hipMemsetAsync((char*)d_ws + WS_CNT * sizeof(float), 0,
                   (BS + 1) * sizeof(int), stream);
    rp_kernel<<<BS * NCHUNK, 256, 0, stream>>>(w, price, psz, ws, out);
}

// Round 7
// 68.046 us; speedup vs baseline: 5.8389x; 5.3682x over previous
//
#include <hip/hip_runtime.h>

#define EPS 1e-8f
#define LAM 0.01f

constexpr int BS = 256;
constexpr int L  = 2048;
constexpr int N  = 128;
constexpr int CHUNK  = 128;          // rows per block; 8 groups x 16 consecutive rows
constexpr int NCHUNK = L / CHUNK;    // 16

typedef float v4f __attribute__((ext_vector_type(4)));

// ws layout (float indices):
//   [0         .. BS*NCHUNK)    = S1 partial per (batch, chunk)
//   [BS*NCHUNK .. 2*BS*NCHUNK)  = S2 partial per (batch, chunk)
// Blocks write only live chunks; finalize reads only live chunks, so no
// pre-zeroing is needed and every replay rewrites the same slots.

__device__ __forceinline__ v4f ld4(const float* p) {
    return *reinterpret_cast<const v4f*>(p);
}

__device__ __forceinline__ float rowdot(const v4f wv, const v4f pi, const v4f pj) {
    float acc = 0.0f;
    #pragma unroll
    for (int i = 0; i < 4; ++i) {
        float r = (pj[i] - pi[i]) * __builtin_amdgcn_rcpf(pi[i]);
        r = (r <= 2.0f) ? r : 0.0f;
        acc += wv[i] * r;
    }
    return acc;
}

__global__ __launch_bounds__(256) void rp_kernel(
    const float* __restrict__ w,      // [BS][L][N]
    const float* __restrict__ price,  // [BS][L+1][N]
    const int*  __restrict__ pred_sz, // [BS]
    float* __restrict__ ws)
{
    const int b     = blockIdx.x / NCHUNK;
    const int chunk = blockIdx.x % NCHUNK;
    const int n     = pred_sz[b];

    const int start = chunk * CHUNK;
    if (start >= n) return;                 // dead block: no loads, no writes
    const int end = min(start + CHUNK, n);

    const int tid  = threadIdx.x;
    const int grp  = tid >> 5;
    const int lane = tid & 31;

    const int rs = start + grp * 16;        // this group's 16 consecutive rows
    const int re = min(rs + 16, end);

    float s1 = 0.0f, s2 = 0.0f;

    if (re - rs == 16) {
        // ---- fast path: 16 full rows as two 8-row batches; all 16+1 loads of a
        // batch are issued back-to-back (sched_barrier pins them ahead of the
        // compute), giving ~16 outstanding loads per wave. ----
        const float* wp = w     + ((size_t)b * L       + rs) * N + lane * 4;
        const float* pp = price + ((size_t)b * (L + 1) + rs) * N + lane * 4;

        v4f pv0 = ld4(pp);                   // price row rs
        #pragma unroll
        for (int half = 0; half < 2; ++half) {
            v4f pjv[8], wvv[8];
            #pragma unroll
            for (int r = 0; r < 8; ++r) {
                const int rr = half * 8 + r;
                pjv[r] = ld4(pp + (size_t)(rr + 1) * N);
                wvv[r] = ld4(wp + (size_t)rr * N);
            }
            __builtin_amdgcn_sched_barrier(0);   // all loads issued before compute

            float A[8];
            #pragma unroll
            for (int r = 0; r < 8; ++r) {
                const v4f pi = (r == 0) ? pv0 : pjv[r - 1];
                A[r] = rowdot(wvv[r], pi, pjv[r]);
            }
            pv0 = pjv[7];                    // carried into next batch

            // Butterfly transpose-reduce over 8 rows x 32 lanes.
            #pragma unroll
            for (int k = 0; k < 3; ++k) {
                const int  m  = 1 << k;
                const bool hi = (lane & m) != 0;
                #pragma unroll
                for (int t = 0; t < (4 >> k); ++t) {
                    const float send = hi ? A[2 * t] : A[2 * t + 1];
                    const float recv = __shfl_xor(send, m);
                    A[t] = (hi ? A[2 * t + 1] : A[2 * t]) + recv;
                }
            }
            float v = A[0] + __shfl_xor(A[0], 8);
            v += __shfl_xor(v, 16);
            const float vm = ((lane & 24) == 0) ? v : 0.0f;  // keep 1 of 4 copies
            s1 += vm;
            s2 += vm * vm;
        }
    } else if (rs < end) {
        // ---- tail path: < 16 rows (at most one group per batch) ----
        const float* wp = w     + ((size_t)b * L       + rs) * N + lane * 4;
        const float* pp = price + ((size_t)b * (L + 1) + rs) * N + lane * 4;
        for (int l = rs; l < re; ++l, wp += N, pp += N) {
            const v4f pi = ld4(pp);
            const v4f pj = ld4(pp + N);
            const v4f wv = ld4(wp);
            float acc = rowdot(wv, pi, pj);
            #pragma unroll
            for (int m = 1; m < 32; m <<= 1)
                acc += __shfl_xor(acc, m);
            if (lane == 0) { s1 += acc; s2 += acc * acc; }
        }
    }

    // Reduce s1/s2 across group, then across the 8 groups.
    #pragma unroll
    for (int m = 1; m < 32; m <<= 1) {
        s1 += __shfl_xor(s1, m);
        s2 += __shfl_xor(s2, m);
    }
    __shared__ float ls1[8], ls2[8];
    if (lane == 0) { ls1[grp] = s1; ls2[grp] = s2; }
    __syncthreads();
    if (tid == 0) {
        float t1 = 0.0f, t2 = 0.0f;
        #pragma unroll
        for (int i = 0; i < 8; ++i) { t1 += ls1[i]; t2 += ls2[i]; }
        ws[b * NCHUNK + chunk]               = t1;
        ws[BS * NCHUNK + b * NCHUNK + chunk] = t2;
    }
}

__global__ __launch_bounds__(256) void final_kernel(
    const float* __restrict__ ws,
    const int*  __restrict__ pred_sz,
    float* __restrict__ out)
{
    const int b = threadIdx.x;   // 256 threads, one per batch
    const int ni = pred_sz[b];
    const int nc = (ni + CHUNK - 1) / CHUNK;   // live chunks for this batch

    float s1 = 0.0f, s2 = 0.0f;
    for (int c = 0; c < nc; ++c) {
        s1 += ws[b * NCHUNK + c];
        s2 += ws[BS * NCHUNK + b * NCHUNK + c];
    }

    const float n     = (float)ni;
    const float E     = s1 / n;
    const float var   = (s2 - n * E * E) / (n - 1.0f);
    const float denom = sqrtf(var + EPS);
    const float sharpe      = E / denom;
    const float sharpe_list = E - LAM / denom;

    __shared__ float red[4][BS];
    red[0][b] = sharpe_list;
    red[1][b] = sharpe;
    red[2][b] = E;
    red[3][b] = var;
    __syncthreads();

    #pragma unroll
    for (int s = BS / 2; s > 0; s >>= 1) {
        if (b < s) {
            red[0][b] += red[0][b + s];
            red[1][b] += red[1][b + s];
            red[2][b] += red[2][b + s];
            red[3][b] += red[3][b + s];
        }
        __syncthreads();
    }

    if (b == 0) {
        out[0] = -red[0][0] / (float)BS;
        out[1] = -red[1][0] / (float)BS;
        out[2] =  red[2][0] / (float)BS;
        out[3] =  red[3][0] / (float)BS;
    }
}

extern "C" void kernel_launch(void* const* d_in, const int* in_sizes, int n_in,
                              void* d_out, int out_size, void* d_ws, size_t ws_size,
                              hipStream_t stream) {
    const float* w     = (const float*)d_in[0];  // pred_weights [256][2048][128]
    const float* price = (const float*)d_in[1];  // price_list   [256][2049][128]
    const int*   psz   = (const int*)d_in[2];    // pred_sz      [256]
    float* out = (float*)d_out;
    float* ws  = (float*)d_ws;

    rp_kernel<<<BS * NCHUNK, 256, 0, stream>>>(w, price, psz, ws);
    final_kernel<<<1, BS, 0, stream>>>(ws, psz, out);
}